// Round 1
// 171.588 us; speedup vs baseline: 1.0398x; 1.0398x over previous
//
#include <hip/hip_runtime.h>

// --- MFMA fp16 LSTM, skewed pipeline, Round 12: 2-blocks-per-CU split ---
// r11 structure (105us): 1024-thr block = 16 waves lockstep, 1 block/CU.
// Counters: VALUBusy 54% (=4.7k/8.7k phase), MfmaUtil 20%, LDS 4.3k (16x
// redundant B-panel reads), ~50% pipe overlap due to single barrier group.
// r12 changes:
//  (a) block split: 512 thr / 8 waves / 32 batch, 512 blocks, 2 blocks/CU.
//      Each wave owns 2 m-tiles (A-frags 56 VGPR; __launch_bounds__(512,4)
//      caps at 128). B-frag reads are m-independent -> per-CU LDS read
//      traffic halves; the two blocks barrier independently -> async
//      inter-block pipe interleave (attacks the 50% overlap loss).
//  (b) gate math: common-denominator c-update (1 rcp instead of 3) and
//      fused sigma(o)*tanh(c) (1 rcp instead of 2): 10 -> 7 trans per h.
// Phase p: layer1(t=p) reads h0(p),h1(p-1); layer0(t=p+1) reads x(p+1),h0(p)
// [shared h0 B-frags]; 29 barriers. Weights pre-scaled: i/f/o rows by -log2e,
// g rows by +2log2e -> bare exp2. B panels frag-linear (conflict-free b128).

typedef _Float16 half8 __attribute__((ext_vector_type(8)));
typedef float floatx4 __attribute__((ext_vector_type(4)));

#define NFRAG 112
#define WS_BIAS_OFF (NFRAG * 1024)
#define K2 2.8853900817779268f      // 2*log2(e)

#if __has_builtin(__builtin_amdgcn_exp2f)
#define EXP2(v) __builtin_amdgcn_exp2f(v)
#else
#define EXP2(v) __expf(0.6931471805599453f * (v))
#endif
#define RCP(v) __builtin_amdgcn_rcpf(v)

__global__ void prep_kernel(const float* __restrict__ Wih0, const float* __restrict__ Whh0,
                            const float* __restrict__ bih0, const float* __restrict__ bhh0,
                            const float* __restrict__ Wih1, const float* __restrict__ Whh1,
                            const float* __restrict__ bih1, const float* __restrict__ bhh1,
                            _Float16* __restrict__ wA, float* __restrict__ wBias) {
    int idx = blockIdx.x * blockDim.x + threadIdx.x;
    if (idx < NFRAG * 512) {
        int f = idx >> 9, slot = idx & 511;
        int lane = slot >> 3, j = slot & 7;
        int mt, kt, layer;
        if (f < 48) { layer = 0; mt = f / 3; kt = f % 3; }
        else        { layer = 1; int f2 = f - 48; mt = f2 >> 2; kt = f2 & 3; }
        int m = mt * 16 + (lane & 15);
        int k = kt * 32 + (lane >> 4) * 8 + j;
        int u = m >> 2, g = m & 3;
        int row = g * 64 + u;
        float v;
        if (layer == 0) {
            if (k < 28)       v = Wih0[row * 28 + k];
            else if (k == 28) v = bih0[row] + bhh0[row];
            else if (k < 32)  v = 0.f;
            else              v = Whh0[row * 64 + (k - 32)];
        } else {
            if (k < 64)       v = Wih1[row * 64 + k];
            else              v = Whh1[row * 64 + (k - 64)];
        }
        float s = (g == 2) ? K2 : -1.4426950408889634f;
        wA[idx] = (_Float16)(v * s);
    } else if (idx < NFRAG * 512 + 256) {
        int m = idx - NFRAG * 512;
        int g = m & 3;
        int row = g * 64 + (m >> 2);
        float s = (g == 2) ? K2 : -1.4426950408889634f;
        wBias[m] = (bih1[row] + bhh1[row]) * s;
    }
}

// Breadth-first N-tile gate batch on PRE-SCALED accs.
// ei=e^{-ai}, ef=e^{-af}, eg=e^{+2ag}, eo=e^{-ao}.
// cn = c*sig(f)+sig(i)*tanh(g) = [c*pg*pi + (eg-1)*pf] / (pf*pg*pi)   (1 rcp)
// h  = sig(o)*tanh(cn) = (ec-1)/(ec*po+po), ec=e^{2cn}                 (1 rcp)
template <int N>
__device__ __forceinline__ void gate_batch(const floatx4* acc, float* c,
                                           _Float16* const* planes, const int* offs) {
    float ei[N], ef[N], eg[N], eo[N];
    #pragma unroll
    for (int i = 0; i < N; ++i) {
        floatx4 a = acc[i];
        ei[i] = EXP2(a[0]);
        ef[i] = EXP2(a[1]);
        eg[i] = EXP2(a[2]);
        eo[i] = EXP2(a[3]);
    }
    float num[N], rd[N], po[N];
    #pragma unroll
    for (int i = 0; i < N; ++i) {
        float pi = 1.0f + ei[i];
        float pf = 1.0f + ef[i];
        float pg = 1.0f + eg[i];
        po[i] = 1.0f + eo[i];
        float m = pg * pi;
        num[i] = c[i] * m + (eg[i] - 1.0f) * pf;
        rd[i]  = RCP(pf * m);
    }
    float ec[N];
    #pragma unroll
    for (int i = 0; i < N; ++i) {
        float cn = num[i] * rd[i];
        c[i] = cn;
        ec[i] = EXP2(K2 * cn);
    }
    #pragma unroll
    for (int i = 0; i < N; ++i) {
        float r2 = RCP(ec[i] * po[i] + po[i]);
        float h = (ec[i] - 1.0f) * r2;
        planes[i][offs[i]] = (_Float16)h;
    }
}

__launch_bounds__(512, 4)
__global__ void lstm_mfma(const float* __restrict__ x,
                          const _Float16* __restrict__ wA,
                          const float* __restrict__ wBias,
                          const float* __restrict__ Wlin, const float* __restrict__ blin,
                          float* __restrict__ out) {
    __shared__ __align__(16) _Float16 h0p[2][2048];  // [parity][frag-linear]
    __shared__ __align__(16) _Float16 h1p[2][2048];
    __shared__ __align__(16) _Float16 xb[2][1024];
    __shared__ float wlin_s[640];
    __shared__ float blin_s[10];

    const int lane = threadIdx.x;
    const int w    = threadIdx.y;      // 0..7
    const int tid  = w * 64 + lane;
    const int quad = lane >> 4;
    const int col  = lane & 15;

    // ---- A fragments: wave owns m-tiles MT = 2w+j, units u = MT*4+quad ----
    half8 A0[2][3], A1[2][4];
    floatx4 bias1[2];
    int hwr[2][2];
    #pragma unroll
    for (int j = 0; j < 2; ++j) {
        const int MT = 2 * w + j;
        #pragma unroll
        for (int kt = 0; kt < 3; ++kt)
            A0[j][kt] = *(const half8*)(wA + (MT * 3 + kt) * 512 + lane * 8);
        #pragma unroll
        for (int kt = 0; kt < 4; ++kt)
            A1[j][kt] = *(const half8*)(wA + (48 + MT * 4 + kt) * 512 + lane * 8);
        const int u = MT * 4 + quad;
        bias1[j] = *(const floatx4*)(wBias + u * 4);
        #pragma unroll
        for (int in = 0; in < 2; ++in)
            hwr[j][in] = (in * 2 + (u >> 5)) * 512 + (((u >> 3) & 3) * 16 + col) * 8 + (u & 7);
    }

    // ---- t-invariant LDS read offsets ----
    int xrd[2], hrd[2][2];
    #pragma unroll
    for (int in = 0; in < 2; ++in) {
        xrd[in] = in * 512 + lane * 8;
        #pragma unroll
        for (int kt = 0; kt < 2; ++kt) hrd[kt][in] = (in * 2 + kt) * 512 + lane * 8;
    }

    // ---- x staging: thread covers b=tid>>5 and b+16, i=tid&31 ----
    const int xi = tid & 31;
    const bool xvalid = xi < 28;
    const int xbi = tid >> 5;          // 0..15
    const float* xg = x + (blockIdx.x * 32 + xbi) * 784 + xi;
    const int xstg = ((xi >> 3) * 16 + xbi) * 8 + (xi & 7);   // in=0; +512 for in=1

    // ---- init: zero h(-1) planes, stage x(0) ----
    {
        ((int*)&h0p[1][0])[tid * 2 + 0] = 0;
        ((int*)&h0p[1][0])[tid * 2 + 1] = 0;
        ((int*)&h1p[1][0])[tid * 2 + 0] = 0;
        ((int*)&h1p[1][0])[tid * 2 + 1] = 0;
        float xv0 = xvalid ? xg[0] : 0.f;
        float xv1 = xvalid ? xg[16 * 784] : 0.f;
        xb[0][xstg]       = (xi == 28) ? (_Float16)1.0f : (_Float16)xv0;
        xb[0][xstg + 512] = (xi == 28) ? (_Float16)1.0f : (_Float16)xv1;
    }
    __syncthreads();

    float c0[2][2] = {{0.f, 0.f}, {0.f, 0.f}};
    float c1[2][2] = {{0.f, 0.f}, {0.f, 0.f}};

    for (int p = -1; p <= 27; ++p) {
        const int pr  = p & 1;
        const int pr1 = pr ^ 1;
        const bool doL0 = (p < 27);
        const bool doL1 = (p >= 0);

        // (1) global prefetch x(p+2)
        float xn0 = 0.f, xn1 = 0.f;
        if (p <= 25 && xvalid) {
            xn0 = xg[(p + 2) * 28];
            xn1 = xg[16 * 784 + (p + 2) * 28];
        }

        // (2) up-front B-frag reads: bx + bh0 (6 b128)
        half8 bx[2], bh0[2][2];
        if (doL0) {
            #pragma unroll
            for (int in = 0; in < 2; ++in)
                bx[in] = *(const half8*)&xb[pr1][xrd[in]];
        }
        #pragma unroll
        for (int kt = 0; kt < 2; ++kt)
            #pragma unroll
            for (int in = 0; in < 2; ++in)
                bh0[kt][in] = *(const half8*)&h0p[pr][hrd[kt][in]];

        // (3) L0 MFMAs + L1 h0-part MFMAs (consume bx, bh0)
        floatx4 acc0[2][2], acc1[2][2];
        if (doL0) {
            #pragma unroll
            for (int j = 0; j < 2; ++j)
                #pragma unroll
                for (int in = 0; in < 2; ++in) {
                    acc0[j][in] = __builtin_amdgcn_mfma_f32_16x16x32_f16(
                                      A0[j][0], bx[in], (floatx4){0.f, 0.f, 0.f, 0.f}, 0, 0, 0);
                    #pragma unroll
                    for (int kt = 0; kt < 2; ++kt)
                        acc0[j][in] = __builtin_amdgcn_mfma_f32_16x16x32_f16(
                                          A0[j][kt + 1], bh0[kt][in], acc0[j][in], 0, 0, 0);
                }
        }
        if (doL1) {
            #pragma unroll
            for (int j = 0; j < 2; ++j)
                #pragma unroll
                for (int in = 0; in < 2; ++in) {
                    acc1[j][in] = bias1[j];
                    #pragma unroll
                    for (int kt = 0; kt < 2; ++kt)
                        acc1[j][in] = __builtin_amdgcn_mfma_f32_16x16x32_f16(
                                          A1[j][kt], bh0[kt][in], acc1[j][in], 0, 0, 0);
                }

            // (4) bh1 reads then L1 tail MFMAs
            half8 bh1[2][2];
            #pragma unroll
            for (int kt = 0; kt < 2; ++kt)
                #pragma unroll
                for (int in = 0; in < 2; ++in)
                    bh1[kt][in] = *(const half8*)&h1p[pr1][hrd[kt][in]];
            #pragma unroll
            for (int j = 0; j < 2; ++j)
                #pragma unroll
                for (int kt = 0; kt < 2; ++kt)
                    #pragma unroll
                    for (int in = 0; in < 2; ++in)
                        acc1[j][in] = __builtin_amdgcn_mfma_f32_16x16x32_f16(
                                          A1[j][kt + 2], bh1[kt][in], acc1[j][in], 0, 0, 0);
        }

        // (5) gates: one merged breadth-first batch
        if (doL0 && doL1) {
            floatx4 a8[8] = {acc0[0][0], acc0[0][1], acc0[1][0], acc0[1][1],
                             acc1[0][0], acc1[0][1], acc1[1][0], acc1[1][1]};
            float   cc[8] = {c0[0][0], c0[0][1], c0[1][0], c0[1][1],
                             c1[0][0], c1[0][1], c1[1][0], c1[1][1]};
            _Float16* pl[8] = {h0p[pr1], h0p[pr1], h0p[pr1], h0p[pr1],
                               h1p[pr],  h1p[pr],  h1p[pr],  h1p[pr]};
            int offs[8] = {hwr[0][0], hwr[0][1], hwr[1][0], hwr[1][1],
                           hwr[0][0], hwr[0][1], hwr[1][0], hwr[1][1]};
            gate_batch<8>(a8, cc, pl, offs);
            c0[0][0] = cc[0]; c0[0][1] = cc[1]; c0[1][0] = cc[2]; c0[1][1] = cc[3];
            c1[0][0] = cc[4]; c1[0][1] = cc[5]; c1[1][0] = cc[6]; c1[1][1] = cc[7];
        } else if (doL0) {
            floatx4 a4[4] = {acc0[0][0], acc0[0][1], acc0[1][0], acc0[1][1]};
            float   cc[4] = {c0[0][0], c0[0][1], c0[1][0], c0[1][1]};
            _Float16* pl[4] = {h0p[pr1], h0p[pr1], h0p[pr1], h0p[pr1]};
            int offs[4] = {hwr[0][0], hwr[0][1], hwr[1][0], hwr[1][1]};
            gate_batch<4>(a4, cc, pl, offs);
            c0[0][0] = cc[0]; c0[0][1] = cc[1]; c0[1][0] = cc[2]; c0[1][1] = cc[3];
        } else {
            floatx4 a4[4] = {acc1[0][0], acc1[0][1], acc1[1][0], acc1[1][1]};
            float   cc[4] = {c1[0][0], c1[0][1], c1[1][0], c1[1][1]};
            _Float16* pl[4] = {h1p[pr], h1p[pr], h1p[pr], h1p[pr]};
            int offs[4] = {hwr[0][0], hwr[0][1], hwr[1][0], hwr[1][1]};
            gate_batch<4>(a4, cc, pl, offs);
            c1[0][0] = cc[0]; c1[0][1] = cc[1]; c1[1][0] = cc[2]; c1[1][1] = cc[3];
        }

        // (6) x staging, then barrier
        if (p <= 25) {
            xb[pr][xstg]       = (xi == 28) ? (_Float16)1.0f : (_Float16)xn0;
            xb[pr][xstg + 512] = (xi == 28) ? (_Float16)1.0f : (_Float16)xn1;
        }
        __syncthreads();
    }

    // ---- epilogue: out = h1(27) @ Wlin^T + blin ----
    wlin_s[tid] = Wlin[tid];
    if (tid < 128) wlin_s[512 + tid] = Wlin[512 + tid];
    if (tid < 10)  blin_s[tid] = blin[tid];
    __syncthreads();
    if (tid < 320) {
        int b = tid / 10, o = tid - b * 10;
        float a = blin_s[o];
        #pragma unroll 8
        for (int uu = 0; uu < 64; ++uu) {
            float hv = (float)h1p[1][((b >> 4) * 2 + (uu >> 5)) * 512 + (((uu >> 3) & 3) * 16 + (b & 15)) * 8 + (uu & 7)];
            a += wlin_s[o * 64 + uu] * hv;
        }
        out[(blockIdx.x * 32 + b) * 10 + o] = a;
    }
}

extern "C" void kernel_launch(void* const* d_in, const int* in_sizes, int n_in,
                              void* d_out, int out_size, void* d_ws, size_t ws_size,
                              hipStream_t stream) {
    const float* x    = (const float*)d_in[0];
    const float* Wih0 = (const float*)d_in[1];
    const float* Whh0 = (const float*)d_in[2];
    const float* bih0 = (const float*)d_in[3];
    const float* bhh0 = (const float*)d_in[4];
    const float* Wih1 = (const float*)d_in[5];
    const float* Whh1 = (const float*)d_in[6];
    const float* bih1 = (const float*)d_in[7];
    const float* bhh1 = (const float*)d_in[8];
    const float* Wlin = (const float*)d_in[9];
    const float* blin = (const float*)d_in[10];
    float* out = (float*)d_out;

    _Float16* wA    = (_Float16*)d_ws;
    float*    wBias = (float*)((char*)d_ws + WS_BIAS_OFF);

    prep_kernel<<<225, 256, 0, stream>>>(Wih0, Whh0, bih0, bhh0,
                                         Wih1, Whh1, bih1, bhh1, wA, wBias);
    lstm_mfma<<<512, dim3(64, 8), 0, stream>>>(x, wA, wBias, Wlin, blin, out);
}